// Round 5
// baseline (664.027 us; speedup 1.0000x reference)
//
#include <hip/hip_runtime.h>
#include <hip/hip_bf16.h>
#include <stdint.h>

typedef short s16x8 __attribute__((ext_vector_type(8)));
typedef float f32x4 __attribute__((ext_vector_type(4)));
typedef unsigned short u16;
typedef unsigned int u32;
typedef unsigned long long u64;

__device__ __forceinline__ float bf2f(u16 v){
  union { u32 u; float f; } c; c.u = ((u32)v) << 16; return c.f;
}

__device__ __forceinline__ u16 f2bf(float f){
  u32 u = __float_as_uint(f);
  u32 r = (u + 0x7FFFu + ((u >> 16) & 1u)) >> 16;   // round-to-nearest-even
  return (u16)r;
}

__device__ __forceinline__ uint4 pack8(float4 a, float4 b){
  union { uint4 v; u16 s[8]; } o;
  o.s[0]=f2bf(a.x); o.s[1]=f2bf(a.y); o.s[2]=f2bf(a.z); o.s[3]=f2bf(a.w);
  o.s[4]=f2bf(b.x); o.s[5]=f2bf(b.y); o.s[6]=f2bf(b.z); o.s[7]=f2bf(b.w);
  return o.v;
}

// ---------------- dtype detector: 1 wave, writes flag (1 = fp32 inputs) ----------------
__global__ __launch_bounds__(64) void k_detect(const u32* __restrict__ x, int* __restrict__ flag){
  int lane = threadIdx.x;
  int cnt = 0;
  for (int i = lane; i < 4096; i += 64){
    u32 w = x[i];
    int ex = (w >> 7) & 0xFF;          // exponent of LOW u16 viewed as bf16
    cnt += (ex >= 140) ? 1 : 0;        // bf16 N(0,1): never; fp32 mantissa bits: ~45%
  }
  #pragma unroll
  for (int off = 32; off; off >>= 1) cnt += __shfl_xor(cnt, off, 64);
  if (lane == 0) *flag = (cnt > 256) ? 1 : 0;
}

// ---------------- flag-aware zero-fill of d_out ----------------
__global__ __launch_bounds__(256) void k_zero(uint4* __restrict__ out, const int* __restrict__ flag,
                                              int out_size){
  int is_f32 = *flag;
  size_t words = (size_t)out_size >> (is_f32 ? 0 : 1);
  size_t n4 = words >> 2;
  size_t i = (size_t)blockIdx.x * 256 + threadIdx.x;
  uint4 z = make_uint4(0, 0, 0, 0);
  for (; i < n4; i += (size_t)gridDim.x * 256) out[i] = z;
}

// ---------------- x -> bf16 copy/convert ----------------
__global__ __launch_bounds__(256) void k_cvt_x(const void* __restrict__ xv, const int* __restrict__ flag,
                                               u16* __restrict__ xb){
  int is_f32 = *flag;
  size_t base = ((size_t)blockIdx.x * 256 + threadIdx.x) << 3;   // 8 elems/thread
  if (is_f32){
    const float* xf = (const float*)xv;
    float4 a = *(const float4*)(xf + base);
    float4 b = *(const float4*)(xf + base + 4);
    *(uint4*)(xb + base) = pack8(a, b);
  } else {
    *(uint4*)(xb + base) = *(const uint4*)((const u16*)xv + base);
  }
}

// ---------------- W (e,d,f) -> WT bf16 (e,f,d) transpose/convert ----------------
__global__ __launch_bounds__(256) void k_cvt_wt(const void* __restrict__ Wv, const int* __restrict__ flag,
                                                u16* __restrict__ WT){
  __shared__ u16 tile[64][72];
  int is_f32 = *flag;
  int bx = blockIdx.x;
  int e = bx >> 8, t2 = bx & 255;
  int td = (t2 >> 4) << 6, tf = (t2 & 15) << 6;
  int tid = threadIdx.x;
  #pragma unroll
  for (int i = 0; i < 2; i++){
    int id = tid + (i << 8);
    int row = id >> 3, c8 = id & 7;
    size_t src = ((size_t)(e*1024 + td + row))*1024 + tf + (c8 << 3);
    uint4 v;
    if (is_f32){
      const float* wf = (const float*)Wv;
      v = pack8(*(const float4*)(wf + src), *(const float4*)(wf + src + 4));
    } else {
      v = *(const uint4*)((const u16*)Wv + src);
    }
    *(uint4*)&tile[row][c8 << 3] = v;
  }
  __syncthreads();
  #pragma unroll
  for (int i = 0; i < 2; i++){
    int id = tid + (i << 8);
    int frow = id >> 3, c8 = id & 7;
    union { uint4 v; u16 s[8]; } o;
    #pragma unroll
    for (int j = 0; j < 8; j++) o.s[j] = tile[(c8 << 3) + j][frow];
    *(uint4*)(WT + ((size_t)(e*1024 + tf + frow))*1024 + td + (c8 << 3)) = o.v;
  }
}

// ---------------- gate logits: (B,N,E) fp32 ----------------
__global__ __launch_bounds__(256) void k_logits(const void* __restrict__ xv, const void* __restrict__ gwv,
                                                const int* __restrict__ flag, float* __restrict__ logits){
  int is_f32 = *flag;
  int tid  = threadIdx.x;
  int wave = tid >> 6, lane = tid & 63;
  int token = (blockIdx.x << 2) + wave;
  float xf[16];
  float acc[8];
  #pragma unroll
  for (int e = 0; e < 8; e++) acc[e] = 0.f;

  if (is_f32){
    const float* xr = (const float*)xv + ((size_t)token << 10) + (lane << 4);
    #pragma unroll
    for (int q = 0; q < 4; q++){
      float4 v = *(const float4*)(xr + (q << 2));
      xf[q*4+0]=v.x; xf[q*4+1]=v.y; xf[q*4+2]=v.z; xf[q*4+3]=v.w;
    }
    const float* gw = (const float*)gwv;
    #pragma unroll
    for (int j = 0; j < 16; j++){
      const float* wr = gw + (((size_t)(lane << 4) + j) << 3);
      float4 w0 = *(const float4*)wr;
      float4 w1 = *(const float4*)(wr + 4);
      float xvv = xf[j];
      acc[0] += xvv*w0.x; acc[1] += xvv*w0.y; acc[2] += xvv*w0.z; acc[3] += xvv*w0.w;
      acc[4] += xvv*w1.x; acc[5] += xvv*w1.y; acc[6] += xvv*w1.z; acc[7] += xvv*w1.w;
    }
  } else {
    const u16* xr = (const u16*)xv + ((size_t)token << 10) + (lane << 4);
    union { uint4 v; u16 s[8]; } xa, xb;
    xa.v = *(const uint4*)xr;
    xb.v = *(const uint4*)(xr + 8);
    #pragma unroll
    for (int j = 0; j < 8; j++){ xf[j] = bf2f(xa.s[j]); xf[8 + j] = bf2f(xb.s[j]); }
    const u16* gw = (const u16*)gwv;
    #pragma unroll
    for (int j = 0; j < 16; j++){
      union { uint4 v; u16 s[8]; } wu;
      wu.v = *(const uint4*)(gw + (((lane << 4) + j) << 3));
      float xvv = xf[j];
      #pragma unroll
      for (int e = 0; e < 8; e++) acc[e] += xvv * bf2f(wu.s[e]);
    }
  }
  #pragma unroll
  for (int off = 32; off; off >>= 1){
    #pragma unroll
    for (int e = 0; e < 8; e++) acc[e] += __shfl_xor(acc[e], off, 64);
  }
  if (lane == 0){
    float4 a0 = make_float4(acc[0], acc[1], acc[2], acc[3]);
    float4 a1 = make_float4(acc[4], acc[5], acc[6], acc[7]);
    float* op = logits + ((size_t)token << 3);
    *(float4*)op = a0;
    *(float4*)(op + 4) = a1;
  }
}

// ---------------- sinkhorn: in-place on (N,E) per batch ----------------
__global__ __launch_bounds__(1024) void k_sinkhorn(float* __restrict__ gates){
  __shared__ float red[1024];
  __shared__ float colm[8];
  __shared__ float coll[8];
  int b = blockIdx.x, t = threadIdx.x;
  int e = t & 7;
  float* gb = gates + (size_t)b * (4096 * 8);
  float c[32];
  #pragma unroll
  for (int q = 0; q < 32; q++){
    float v = gb[t + (q << 10)];
    c[q] = logf(fmaxf(v, 1e-6f));
  }
  for (int it = 0; it < 8; it++){
    float m = c[0];
    #pragma unroll
    for (int q = 1; q < 32; q++) m = fmaxf(m, c[q]);
    red[t] = m;
    __syncthreads();
    for (int off = 512; off >= 8; off >>= 1){
      if (t < off) red[t] = fmaxf(red[t], red[t + off]);
      __syncthreads();
    }
    if (t < 8) colm[t] = red[t];
    __syncthreads();
    float cm = colm[e];
    float s = 0.f;
    #pragma unroll
    for (int q = 0; q < 32; q++) s += expf(c[q] - cm);
    red[t] = s;
    __syncthreads();
    for (int off = 512; off >= 8; off >>= 1){
      if (t < off) red[t] = red[t] + red[t + off];
      __syncthreads();
    }
    if (t < 8) coll[t] = colm[t] + logf(red[t]);
    __syncthreads();
    float cl = coll[e];
    #pragma unroll
    for (int q = 0; q < 32; q++){
      float v = c[q] - cl;
      float rm = v;
      rm = fmaxf(rm, __shfl_xor(rm, 1, 64));
      rm = fmaxf(rm, __shfl_xor(rm, 2, 64));
      rm = fmaxf(rm, __shfl_xor(rm, 4, 64));
      float rs = expf(v - rm);
      rs += __shfl_xor(rs, 1, 64);
      rs += __shfl_xor(rs, 2, 64);
      rs += __shfl_xor(rs, 4, 64);
      float lse = rm + logf(rs);
      c[q] = v - lse;
    }
    __syncthreads();
  }
  #pragma unroll
  for (int q = 0; q < 32; q++) gb[t + (q << 10)] = expf(c[q]);
}

// ---------------- top-512 via exact rank-by-counting (replaces bitonic sort) ----------------
// rank(i) = #{j: v_j > v_i} + #{j<i: v_j == v_i}  == jax top_k order (value desc, index asc)
__global__ __launch_bounds__(512) void k_rank(const float* __restrict__ gates,
                                              int* __restrict__ routed, int* __restrict__ winner){
  __shared__ u32 ord_s[4096];
  int bx = blockIdx.x;           // 256 blocks: (b,e) = bx>>3, slice = bx&7
  int be = bx >> 3;
  int b = be >> 3, e = be & 7;
  int slice = bx & 7;
  int tid = threadIdx.x;
  const float* gb = gates + (size_t)b * (4096 * 8);
  for (int i = tid; i < 4096; i += 512){
    float v = gb[(i << 3) + e];
    u32 fb = __float_as_uint(v);
    ord_s[i] = fb ^ ((fb >> 31) ? 0xFFFFFFFFu : 0x80000000u);   // monotone total order
  }
  __syncthreads();
  int i = (slice << 9) + tid;    // my token
  u32 v = ord_s[i];
  int gt = 0, eq = 0;
  for (int j4 = 0; j4 < 4096; j4 += 8){
    uint4 w0 = *(const uint4*)&ord_s[j4];
    uint4 w1 = *(const uint4*)&ord_s[j4 + 4];
    gt += (w0.x > v) + (w0.y > v) + (w0.z > v) + (w0.w > v)
        + (w1.x > v) + (w1.y > v) + (w1.z > v) + (w1.w > v);
    eq += (w0.x == v) + (w0.y == v) + (w0.z == v) + (w0.w == v)
        + (w1.x == v) + (w1.y == v) + (w1.z == v) + (w1.w == v);
  }
  int rank;
  if (eq == 1){
    rank = gt;                   // unique value (the common case)
  } else {
    int eqlo = 0;
    for (int j = 0; j < i; j++) eqlo += (ord_s[j] == v);
    rank = gt + eqlo;
  }
  if (rank < 512){
    routed[(be << 9) + rank] = i;
    atomicMax(&winner[(b << 12) + i], (rank << 3) | e);   // numpy last-write-wins: max (m,e)
  }
}

// ---------------- fast gathered GEMM: pre-converted bf16 x and (e,f,d) WT ----------------
__global__ __launch_bounds__(256) void k_gemm_fast(const u16* __restrict__ xb, const u16* __restrict__ WT,
                                                   const float* __restrict__ gates,
                                                   const int* __restrict__ routed,
                                                   const int* __restrict__ winner,
                                                   const int* __restrict__ flag,
                                                   void* __restrict__ outv){
  __shared__ u16 As[128 * 32];
  __shared__ u16 Bs[128 * 32];
  __shared__ int   tok_s[128];
  __shared__ float gate_s[128];
  __shared__ int   flg_s[128];
  int is_f32 = *flag;
  int bx = blockIdx.x;
  int gemm = bx >> 5, tile = bx & 31;
  int b = gemm >> 3, e = gemm & 7;
  int mt = tile & 3, nt = tile >> 2;
  int tid = threadIdx.x;
  int w = tid >> 6, lane = tid & 63;
  int quad = lane >> 4, l16 = lane & 15;

  const int* idx_base = routed + (((b << 3) + e) << 9) + (mt << 7);

  if (tid < 128){
    int tok = idx_base[tid];
    int mg  = (mt << 7) + tid;
    int win = winner[(b << 12) + tok];
    tok_s[tid]  = tok;
    flg_s[tid]  = (win == ((mg << 3) | e)) ? 1 : 0;
    gate_s[tid] = gates[((((size_t)b << 12) + tok) << 3) + e];
  }
  __syncthreads();

  int r0 = tid >> 2;            // 0..63
  int ch = tid & 3;             // 16B chunk
  int r1 = r0 + 64;
  const u16* gA0 = xb + ((((size_t)b << 12) + tok_s[r0]) << 10) + (ch << 3);
  const u16* gA1 = xb + ((((size_t)b << 12) + tok_s[r1]) << 10) + (ch << 3);
  int f0 = nt << 7;
  const u16* gB0 = WT + ((((size_t)e << 10) + f0 + r0) << 10) + (ch << 3);
  const u16* gB1 = WT + ((((size_t)e << 10) + f0 + r1) << 10) + (ch << 3);

  f32x4 acc[4][4] = {};
  int wm = (w & 1) << 6, wn = (w >> 1) << 6;

  for (int k0 = 0; k0 < 1024; k0 += 32){
    uint4 a0 = *(const uint4*)(gA0 + k0);
    uint4 a1 = *(const uint4*)(gA1 + k0);
    uint4 b0 = *(const uint4*)(gB0 + k0);
    uint4 b1 = *(const uint4*)(gB1 + k0);
    *(uint4*)&As[(r0 << 5) + (ch << 3)] = a0;
    *(uint4*)&As[(r1 << 5) + (ch << 3)] = a1;
    *(uint4*)&Bs[(r0 << 5) + (ch << 3)] = b0;
    *(uint4*)&Bs[(r1 << 5) + (ch << 3)] = b1;
    __syncthreads();
    s16x8 af[4], bv[4];
    #pragma unroll
    for (int im = 0; im < 4; im++)
      af[im] = *(const s16x8*)&As[((wm + (im << 4) + l16) << 5) + (quad << 3)];
    #pragma unroll
    for (int in = 0; in < 4; in++)
      bv[in] = *(const s16x8*)&Bs[((wn + (in << 4) + l16) << 5) + (quad << 3)];
    __syncthreads();
    #pragma unroll
    for (int im = 0; im < 4; im++){
      #pragma unroll
      for (int in = 0; in < 4; in++)
        acc[im][in] = __builtin_amdgcn_mfma_f32_16x16x32_bf16(af[im], bv[in], acc[im][in], 0, 0, 0);
    }
  }

  #pragma unroll
  for (int im = 0; im < 4; im++){
    #pragma unroll
    for (int r = 0; r < 4; r++){
      int mrow = wm + (im << 4) + (quad << 2) + r;
      if (flg_s[mrow]){
        float g  = gate_s[mrow];
        int tok  = tok_s[mrow];
        size_t obase = ((((size_t)b << 12) + tok) << 10) + f0 + wn + l16;
        if (is_f32){
          float* o32 = (float*)outv;
          #pragma unroll
          for (int in = 0; in < 4; in++) o32[obase + (in << 4)] = acc[im][in][r] * g;
        } else {
          u16* o16 = (u16*)outv;
          #pragma unroll
          for (int in = 0; in < 4; in++) o16[obase + (in << 4)] = f2bf(acc[im][in][r] * g);
        }
      }
    }
  }
}

// ---------------- fallback GEMM (round-4 validated): on-the-fly convert + LDS transpose ----------------
__global__ __launch_bounds__(256) void k_gemm_slow(const void* __restrict__ xv, const void* __restrict__ Wv,
                                                   const float* __restrict__ gates,
                                                   const int* __restrict__ routed,
                                                   const int* __restrict__ winner,
                                                   const int* __restrict__ flag,
                                                   void* __restrict__ outv){
  __shared__ u16 As[128 * 32];
  __shared__ u16 Bw[32 * 132];
  __shared__ u16 Bs[128 * 32];
  __shared__ int   tok_s[128];
  __shared__ float gate_s[128];
  __shared__ int   flg_s[128];
  int is_f32 = *flag;
  int bx = blockIdx.x;
  int gemm = bx >> 5, tile = bx & 31;
  int b = gemm >> 3, e = gemm & 7;
  int mt = tile & 3, nt = tile >> 2;
  int tid = threadIdx.x;
  int w = tid >> 6, lane = tid & 63;
  int quad = lane >> 4, l16 = lane & 15;

  const int* idx_base = routed + (((b << 3) + e) << 9) + (mt << 7);

  if (tid < 128){
    int tok = idx_base[tid];
    int mg  = (mt << 7) + tid;
    int win = winner[(b << 12) + tok];
    tok_s[tid]  = tok;
    flg_s[tid]  = (win == ((mg << 3) | e)) ? 1 : 0;
    gate_s[tid] = gates[((((size_t)b << 12) + tok) << 3) + e];
  }
  __syncthreads();

  int r0 = tid >> 2;
  int ch = tid & 3;
  int r1 = r0 + 64;
  size_t offA0 = ((((size_t)b << 12) + tok_s[r0]) << 10) + (ch << 3);
  size_t offA1 = ((((size_t)b << 12) + tok_s[r1]) << 10) + (ch << 3);
  int f0 = nt << 7;
  int kkB0 = tid >> 4;
  int fcB  = tid & 15;
  size_t offB0 = ((size_t)e << 20) + ((size_t)kkB0 << 10) + f0 + (fcB << 3);
  size_t offB1 = offB0 + ((size_t)16 << 10);
  int f_loc = tid >> 1;
  int half  = tid & 1;

  f32x4 acc[4][4] = {};
  int wm = (w & 1) << 6, wn = (w >> 1) << 6;

  for (int k0 = 0; k0 < 1024; k0 += 32){
    uint4 a0, a1, b0, b1;
    if (is_f32){
      const float* xf = (const float*)xv;
      const float* wf = (const float*)Wv;
      a0 = pack8(*(const float4*)(xf + offA0 + k0), *(const float4*)(xf + offA0 + k0 + 4));
      a1 = pack8(*(const float4*)(xf + offA1 + k0), *(const float4*)(xf + offA1 + k0 + 4));
      b0 = pack8(*(const float4*)(wf + offB0 + ((size_t)k0 << 10)),
                 *(const float4*)(wf + offB0 + ((size_t)k0 << 10) + 4));
      b1 = pack8(*(const float4*)(wf + offB1 + ((size_t)k0 << 10)),
                 *(const float4*)(wf + offB1 + ((size_t)k0 << 10) + 4));
    } else {
      const u16* xh = (const u16*)xv;
      const u16* wh = (const u16*)Wv;
      a0 = *(const uint4*)(xh + offA0 + k0);
      a1 = *(const uint4*)(xh + offA1 + k0);
      b0 = *(const uint4*)(wh + offB0 + ((size_t)k0 << 10));
      b1 = *(const uint4*)(wh + offB1 + ((size_t)k0 << 10));
    }
    *(uint4*)&As[(r0 << 5) + (ch << 3)] = a0;
    *(uint4*)&As[(r1 << 5) + (ch << 3)] = a1;
    *(uint4*)&Bw[kkB0 * 132 + (fcB << 3)] = b0;
    *(uint4*)&Bw[(kkB0 + 16) * 132 + (fcB << 3)] = b1;
    __syncthreads();
    union { uint4 v[2]; u16 s[16]; } tv;
    #pragma unroll
    for (int j = 0; j < 16; j++) tv.s[j] = Bw[((half << 4) + j) * 132 + f_loc];
    *(uint4*)&Bs[(f_loc << 5) + (half << 4)]     = tv.v[0];
    *(uint4*)&Bs[(f_loc << 5) + (half << 4) + 8] = tv.v[1];
    __syncthreads();
    s16x8 af[4], bv[4];
    #pragma unroll
    for (int im = 0; im < 4; im++)
      af[im] = *(const s16x8*)&As[((wm + (im << 4) + l16) << 5) + (quad << 3)];
    #pragma unroll
    for (int in = 0; in < 4; in++)
      bv[in] = *(const s16x8*)&Bs[((wn + (in << 4) + l16) << 5) + (quad << 3)];
    __syncthreads();
    #pragma unroll
    for (int im = 0; im < 4; im++){
      #pragma unroll
      for (int in = 0; in < 4; in++)
        acc[im][in] = __builtin_amdgcn_mfma_f32_16x16x32_bf16(af[im], bv[in], acc[im][in], 0, 0, 0);
    }
  }

  #pragma unroll
  for (int im = 0; im < 4; im++){
    #pragma unroll
    for (int r = 0; r < 4; r++){
      int mrow = wm + (im << 4) + (quad << 2) + r;
      if (flg_s[mrow]){
        float g  = gate_s[mrow];
        int tok  = tok_s[mrow];
        size_t obase = ((((size_t)b << 12) + tok) << 10) + f0 + wn + l16;
        if (is_f32){
          float* o32 = (float*)outv;
          #pragma unroll
          for (int in = 0; in < 4; in++) o32[obase + (in << 4)] = acc[im][in][r] * g;
        } else {
          u16* o16 = (u16*)outv;
          #pragma unroll
          for (int in = 0; in < 4; in++) o16[obase + (in << 4)] = f2bf(acc[im][in][r] * g);
        }
      }
    }
  }
}

extern "C" void kernel_launch(void* const* d_in, const int* in_sizes, int n_in,
                              void* d_out, int out_size, void* d_ws, size_t ws_size,
                              hipStream_t stream){
  const void* x  = d_in[0];   // (4,4096,1024)
  const void* gw = d_in[1];   // (1024,8)
  const void* W  = d_in[2];   // (8,1024,1024)
  char* ws = (char*)d_ws;
  float* gates  = (float*)ws;                               // 524288 B
  int*   winner = (int*)(ws + 524288);                      // 65536 B
  int*   routed = (int*)(ws + 589824);                      // 65536 B
  int*   flag   = (int*)(ws + 655360);                      // 256 B (padded)
  u16*   xb     = (u16*)(ws + 655616);                      // 33554432 B
  u16*   WT     = (u16*)(ws + 655616 + 33554432);           // 16777216 B
  size_t need_fast = 655616ull + 33554432ull + 16777216ull; // ~48.6 MiB
  bool fast = ws_size >= need_fast;

  hipMemsetAsync(winner, 0xFF, 65536, stream);
  hipLaunchKernelGGL(k_detect,   dim3(1),    dim3(64),   0, stream, (const u32*)x, flag);
  hipLaunchKernelGGL(k_zero,     dim3(4096), dim3(256),  0, stream, (uint4*)d_out, flag, out_size);
  hipLaunchKernelGGL(k_logits,   dim3(4096), dim3(256),  0, stream, x, gw, flag, gates);
  hipLaunchKernelGGL(k_sinkhorn, dim3(4),    dim3(1024), 0, stream, gates);
  hipLaunchKernelGGL(k_rank,     dim3(256),  dim3(512),  0, stream, gates, routed, winner);
  if (fast){
    hipLaunchKernelGGL(k_cvt_x,  dim3(8192), dim3(256),  0, stream, x, flag, xb);
    hipLaunchKernelGGL(k_cvt_wt, dim3(2048), dim3(256),  0, stream, W, flag, WT);
    hipLaunchKernelGGL(k_gemm_fast, dim3(1024), dim3(256), 0, stream, xb, WT, gates, routed, winner,
                       flag, d_out);
  } else {
    hipLaunchKernelGGL(k_gemm_slow, dim3(1024), dim3(256), 0, stream, x, W, gates, routed, winner,
                       flag, d_out);
  }
}

// Round 6
// 460.024 us; speedup vs baseline: 1.4435x; 1.4435x over previous
//
#include <hip/hip_runtime.h>
#include <hip/hip_bf16.h>
#include <stdint.h>

typedef short s16x8 __attribute__((ext_vector_type(8)));
typedef float f32x4 __attribute__((ext_vector_type(4)));
typedef unsigned short u16;
typedef unsigned int u32;
typedef unsigned long long u64;

__device__ __forceinline__ float bf2f(u16 v){
  union { u32 u; float f; } c; c.u = ((u32)v) << 16; return c.f;
}

__device__ __forceinline__ u16 f2bf(float f){
  u32 u = __float_as_uint(f);
  u32 r = (u + 0x7FFFu + ((u >> 16) & 1u)) >> 16;   // round-to-nearest-even
  return (u16)r;
}

__device__ __forceinline__ uint4 pack8(float4 a, float4 b){
  union { uint4 v; u16 s[8]; } o;
  o.s[0]=f2bf(a.x); o.s[1]=f2bf(a.y); o.s[2]=f2bf(a.z); o.s[3]=f2bf(a.w);
  o.s[4]=f2bf(b.x); o.s[5]=f2bf(b.y); o.s[6]=f2bf(b.z); o.s[7]=f2bf(b.w);
  return o.v;
}

// ---------------- dtype detector: 1 wave, writes flag (1 = fp32 inputs) ----------------
__global__ __launch_bounds__(64) void k_detect(const u32* __restrict__ x, int* __restrict__ flag){
  int lane = threadIdx.x;
  int cnt = 0;
  for (int i = lane; i < 4096; i += 64){
    u32 w = x[i];
    int ex = (w >> 7) & 0xFF;
    cnt += (ex >= 140) ? 1 : 0;
  }
  #pragma unroll
  for (int off = 32; off; off >>= 1) cnt += __shfl_xor(cnt, off, 64);
  if (lane == 0) *flag = (cnt > 256) ? 1 : 0;
}

// ---------------- flag-aware zero-fill of d_out ----------------
__global__ __launch_bounds__(256) void k_zero(uint4* __restrict__ out, const int* __restrict__ flag,
                                              int out_size){
  int is_f32 = *flag;
  size_t words = (size_t)out_size >> (is_f32 ? 0 : 1);
  size_t n4 = words >> 2;
  size_t i = (size_t)blockIdx.x * 256 + threadIdx.x;
  uint4 z = make_uint4(0, 0, 0, 0);
  for (; i < n4; i += (size_t)gridDim.x * 256) out[i] = z;
}

// ---------------- x -> bf16 copy/convert ----------------
__global__ __launch_bounds__(256) void k_cvt_x(const void* __restrict__ xv, const int* __restrict__ flag,
                                               u16* __restrict__ xb){
  int is_f32 = *flag;
  size_t base = ((size_t)blockIdx.x * 256 + threadIdx.x) << 3;
  if (is_f32){
    const float* xf = (const float*)xv;
    float4 a = *(const float4*)(xf + base);
    float4 b = *(const float4*)(xf + base + 4);
    *(uint4*)(xb + base) = pack8(a, b);
  } else {
    *(uint4*)(xb + base) = *(const uint4*)((const u16*)xv + base);
  }
}

// ---------------- W (e,d,f) -> WT bf16 (e,f,d) transpose/convert ----------------
__global__ __launch_bounds__(256) void k_cvt_wt(const void* __restrict__ Wv, const int* __restrict__ flag,
                                                u16* __restrict__ WT){
  __shared__ u16 tile[64][72];
  int is_f32 = *flag;
  int bx = blockIdx.x;
  int e = bx >> 8, t2 = bx & 255;
  int td = (t2 >> 4) << 6, tf = (t2 & 15) << 6;
  int tid = threadIdx.x;
  #pragma unroll
  for (int i = 0; i < 2; i++){
    int id = tid + (i << 8);
    int row = id >> 3, c8 = id & 7;
    size_t src = ((size_t)(e*1024 + td + row))*1024 + tf + (c8 << 3);
    uint4 v;
    if (is_f32){
      const float* wf = (const float*)Wv;
      v = pack8(*(const float4*)(wf + src), *(const float4*)(wf + src + 4));
    } else {
      v = *(const uint4*)((const u16*)Wv + src);
    }
    *(uint4*)&tile[row][c8 << 3] = v;
  }
  __syncthreads();
  #pragma unroll
  for (int i = 0; i < 2; i++){
    int id = tid + (i << 8);
    int frow = id >> 3, c8 = id & 7;
    union { uint4 v; u16 s[8]; } o;
    #pragma unroll
    for (int j = 0; j < 8; j++) o.s[j] = tile[(c8 << 3) + j][frow];
    *(uint4*)(WT + ((size_t)(e*1024 + tf + frow))*1024 + td + (c8 << 3)) = o.v;
  }
}

// ---------------- gate logits: (B,N,E) fp32 ----------------
__global__ __launch_bounds__(256) void k_logits(const void* __restrict__ xv, const void* __restrict__ gwv,
                                                const int* __restrict__ flag, float* __restrict__ logits){
  int is_f32 = *flag;
  int tid  = threadIdx.x;
  int wave = tid >> 6, lane = tid & 63;
  int token = (blockIdx.x << 2) + wave;
  float xf[16];
  float acc[8];
  #pragma unroll
  for (int e = 0; e < 8; e++) acc[e] = 0.f;

  if (is_f32){
    const float* xr = (const float*)xv + ((size_t)token << 10) + (lane << 4);
    #pragma unroll
    for (int q = 0; q < 4; q++){
      float4 v = *(const float4*)(xr + (q << 2));
      xf[q*4+0]=v.x; xf[q*4+1]=v.y; xf[q*4+2]=v.z; xf[q*4+3]=v.w;
    }
    const float* gw = (const float*)gwv;
    #pragma unroll
    for (int j = 0; j < 16; j++){
      const float* wr = gw + (((size_t)(lane << 4) + j) << 3);
      float4 w0 = *(const float4*)wr;
      float4 w1 = *(const float4*)(wr + 4);
      float xvv = xf[j];
      acc[0] += xvv*w0.x; acc[1] += xvv*w0.y; acc[2] += xvv*w0.z; acc[3] += xvv*w0.w;
      acc[4] += xvv*w1.x; acc[5] += xvv*w1.y; acc[6] += xvv*w1.z; acc[7] += xvv*w1.w;
    }
  } else {
    const u16* xr = (const u16*)xv + ((size_t)token << 10) + (lane << 4);
    union { uint4 v; u16 s[8]; } xa, xb;
    xa.v = *(const uint4*)xr;
    xb.v = *(const uint4*)(xr + 8);
    #pragma unroll
    for (int j = 0; j < 8; j++){ xf[j] = bf2f(xa.s[j]); xf[8 + j] = bf2f(xb.s[j]); }
    const u16* gw = (const u16*)gwv;
    #pragma unroll
    for (int j = 0; j < 16; j++){
      union { uint4 v; u16 s[8]; } wu;
      wu.v = *(const uint4*)(gw + (((lane << 4) + j) << 3));
      float xvv = xf[j];
      #pragma unroll
      for (int e = 0; e < 8; e++) acc[e] += xvv * bf2f(wu.s[e]);
    }
  }
  #pragma unroll
  for (int off = 32; off; off >>= 1){
    #pragma unroll
    for (int e = 0; e < 8; e++) acc[e] += __shfl_xor(acc[e], off, 64);
  }
  if (lane == 0){
    float4 a0 = make_float4(acc[0], acc[1], acc[2], acc[3]);
    float4 a1 = make_float4(acc[4], acc[5], acc[6], acc[7]);
    float* op = logits + ((size_t)token << 3);
    *(float4*)op = a0;
    *(float4*)(op + 4) = a1;
  }
}

// ---------------- sinkhorn: in-place on (N,E) per batch ----------------
__global__ __launch_bounds__(1024) void k_sinkhorn(float* __restrict__ gates){
  __shared__ float red[1024];
  __shared__ float colm[8];
  __shared__ float coll[8];
  int b = blockIdx.x, t = threadIdx.x;
  int e = t & 7;
  float* gb = gates + (size_t)b * (4096 * 8);
  float c[32];
  #pragma unroll
  for (int q = 0; q < 32; q++){
    float v = gb[t + (q << 10)];
    c[q] = logf(fmaxf(v, 1e-6f));
  }
  for (int it = 0; it < 8; it++){
    float m = c[0];
    #pragma unroll
    for (int q = 1; q < 32; q++) m = fmaxf(m, c[q]);
    red[t] = m;
    __syncthreads();
    for (int off = 512; off >= 8; off >>= 1){
      if (t < off) red[t] = fmaxf(red[t], red[t + off]);
      __syncthreads();
    }
    if (t < 8) colm[t] = red[t];
    __syncthreads();
    float cm = colm[e];
    float s = 0.f;
    #pragma unroll
    for (int q = 0; q < 32; q++) s += expf(c[q] - cm);
    red[t] = s;
    __syncthreads();
    for (int off = 512; off >= 8; off >>= 1){
      if (t < off) red[t] = red[t] + red[t + off];
      __syncthreads();
    }
    if (t < 8) coll[t] = colm[t] + logf(red[t]);
    __syncthreads();
    float cl = coll[e];
    #pragma unroll
    for (int q = 0; q < 32; q++){
      float v = c[q] - cl;
      float rm = v;
      rm = fmaxf(rm, __shfl_xor(rm, 1, 64));
      rm = fmaxf(rm, __shfl_xor(rm, 2, 64));
      rm = fmaxf(rm, __shfl_xor(rm, 4, 64));
      float rs = expf(v - rm);
      rs += __shfl_xor(rs, 1, 64);
      rs += __shfl_xor(rs, 2, 64);
      rs += __shfl_xor(rs, 4, 64);
      float lse = rm + logf(rs);
      c[q] = v - lse;
    }
    __syncthreads();
  }
  #pragma unroll
  for (int q = 0; q < 32; q++) gb[t + (q << 10)] = expf(c[q]);
}

// ---------------- top-512 via exact rank-by-counting, v2 ----------------
// rank(i) = #{j<i: v_j >= v_i} + #{j>i: v_j > v_i}  == jax top_k order, single compare per pair.
// Grid: 1024 blocks = 32 (b,e)-columns x 32 slices of 128 tokens. Block: 256 threads.
// Thread: owns 4 consecutive tokens (regs) x 1/8 of the j-range. 16 waves/CU.
__global__ __launch_bounds__(256) void k_rank(const float* __restrict__ gates,
                                              int* __restrict__ routed, int* __restrict__ winner){
  __shared__ u32 ord_s[4096];
  __shared__ u32 cnt_s[1024];    // [js][local_token]
  int bx = blockIdx.x;
  int be = bx >> 5;              // 0..31
  int b = be >> 3, e = be & 7;
  int slice = bx & 31;           // 0..31
  int tid = threadIdx.x;
  const float* gb = gates + (size_t)b * (4096 * 8);
  for (int i = tid; i < 4096; i += 256){
    float v = gb[(i << 3) + e];
    u32 fb = __float_as_uint(v);
    ord_s[i] = fb ^ ((fb >> 31) ? 0xFFFFFFFFu : 0x80000000u);   // monotone total order
  }
  __syncthreads();

  int tg = tid & 31;             // token group: 4 tokens
  int js = tid >> 5;             // j-slice: 0..7, 512 j's each
  int i0 = (slice << 7) + (tg << 2);          // first of my 4 tokens (4-aligned)
  int gchunk = i0 & ~7;                       // the 8-chunk containing all 4 tokens
  u32 v0 = ord_s[i0], v1 = ord_s[i0+1], v2 = ord_s[i0+2], v3 = ord_s[i0+3];
  int jlo = js << 9, jhi = jlo + 512;
  int c0 = 0, c1 = 0, c2 = 0, c3 = 0;

  // span A: chunks entirely below gchunk -> predicate >=
  int endA = min(jhi, gchunk);
  for (int j = jlo; j < endA; j += 8){
    uint4 w0 = *(const uint4*)&ord_s[j];
    uint4 w1 = *(const uint4*)&ord_s[j + 4];
    c0 += (w0.x>=v0)+(w0.y>=v0)+(w0.z>=v0)+(w0.w>=v0)+(w1.x>=v0)+(w1.y>=v0)+(w1.z>=v0)+(w1.w>=v0);
    c1 += (w0.x>=v1)+(w0.y>=v1)+(w0.z>=v1)+(w0.w>=v1)+(w1.x>=v1)+(w1.y>=v1)+(w1.z>=v1)+(w1.w>=v1);
    c2 += (w0.x>=v2)+(w0.y>=v2)+(w0.z>=v2)+(w0.w>=v2)+(w1.x>=v2)+(w1.y>=v2)+(w1.z>=v2)+(w1.w>=v2);
    c3 += (w0.x>=v3)+(w0.y>=v3)+(w0.z>=v3)+(w0.w>=v3)+(w1.x>=v3)+(w1.y>=v3)+(w1.z>=v3)+(w1.w>=v3);
  }
  // span B: chunks entirely above gchunk -> predicate >
  int begB = max(jlo, gchunk + 8);
  for (int j = begB; j < jhi; j += 8){
    uint4 w0 = *(const uint4*)&ord_s[j];
    uint4 w1 = *(const uint4*)&ord_s[j + 4];
    c0 += (w0.x>v0)+(w0.y>v0)+(w0.z>v0)+(w0.w>v0)+(w1.x>v0)+(w1.y>v0)+(w1.z>v0)+(w1.w>v0);
    c1 += (w0.x>v1)+(w0.y>v1)+(w0.z>v1)+(w0.w>v1)+(w1.x>v1)+(w1.y>v1)+(w1.z>v1)+(w1.w>v1);
    c2 += (w0.x>v2)+(w0.y>v2)+(w0.z>v2)+(w0.w>v2)+(w1.x>v2)+(w1.y>v2)+(w1.z>v2)+(w1.w>v2);
    c3 += (w0.x>v3)+(w0.y>v3)+(w0.z>v3)+(w0.w>v3)+(w1.x>v3)+(w1.y>v3)+(w1.z>v3)+(w1.w>v3);
  }
  // boundary chunk (contains my 4 tokens) — element-wise j<i test
  if (gchunk >= jlo && gchunk < jhi){
    int base_off = i0 & 7;       // i0 - gchunk: 0 or 4
    #pragma unroll
    for (int jj = 0; jj < 8; jj++){
      u32 w = ord_s[gchunk + jj];
      c0 += (jj < base_off + 0) ? (w >= v0) : (w > v0);
      c1 += (jj < base_off + 1) ? (w >= v1) : (w > v1);
      c2 += (jj < base_off + 2) ? (w >= v2) : (w > v2);
      c3 += (jj < base_off + 3) ? (w >= v3) : (w > v3);
    }
  }
  int lt = tg << 2;              // local token base
  cnt_s[(js << 7) + lt + 0] = c0;
  cnt_s[(js << 7) + lt + 1] = c1;
  cnt_s[(js << 7) + lt + 2] = c2;
  cnt_s[(js << 7) + lt + 3] = c3;
  __syncthreads();
  if (tid < 128){
    int rank = 0;
    #pragma unroll
    for (int s = 0; s < 8; s++) rank += cnt_s[(s << 7) + tid];
    int i = (slice << 7) + tid;
    if (rank < 512){
      routed[(be << 9) + rank] = i;
      atomicMax(&winner[(b << 12) + i], (rank << 3) | e);   // numpy last-write-wins: max (m,e)
    }
  }
}

// ---------------- fast gathered GEMM: pre-converted bf16 x and (e,f,d) WT ----------------
__global__ __launch_bounds__(256) void k_gemm_fast(const u16* __restrict__ xb, const u16* __restrict__ WT,
                                                   const float* __restrict__ gates,
                                                   const int* __restrict__ routed,
                                                   const int* __restrict__ winner,
                                                   const int* __restrict__ flag,
                                                   void* __restrict__ outv){
  __shared__ u16 As[128 * 32];
  __shared__ u16 Bs[128 * 32];
  __shared__ int   tok_s[128];
  __shared__ float gate_s[128];
  __shared__ int   flg_s[128];
  int is_f32 = *flag;
  int bx = blockIdx.x;
  int gemm = bx >> 5, tile = bx & 31;
  int b = gemm >> 3, e = gemm & 7;
  int mt = tile & 3, nt = tile >> 2;
  int tid = threadIdx.x;
  int w = tid >> 6, lane = tid & 63;
  int quad = lane >> 4, l16 = lane & 15;

  const int* idx_base = routed + (((b << 3) + e) << 9) + (mt << 7);

  if (tid < 128){
    int tok = idx_base[tid];
    int mg  = (mt << 7) + tid;
    int win = winner[(b << 12) + tok];
    tok_s[tid]  = tok;
    flg_s[tid]  = (win == ((mg << 3) | e)) ? 1 : 0;
    gate_s[tid] = gates[((((size_t)b << 12) + tok) << 3) + e];
  }
  __syncthreads();

  int r0 = tid >> 2;
  int ch = tid & 3;
  int r1 = r0 + 64;
  const u16* gA0 = xb + ((((size_t)b << 12) + tok_s[r0]) << 10) + (ch << 3);
  const u16* gA1 = xb + ((((size_t)b << 12) + tok_s[r1]) << 10) + (ch << 3);
  int f0 = nt << 7;
  const u16* gB0 = WT + ((((size_t)e << 10) + f0 + r0) << 10) + (ch << 3);
  const u16* gB1 = WT + ((((size_t)e << 10) + f0 + r1) << 10) + (ch << 3);

  f32x4 acc[4][4] = {};
  int wm = (w & 1) << 6, wn = (w >> 1) << 6;

  for (int k0 = 0; k0 < 1024; k0 += 32){
    uint4 a0 = *(const uint4*)(gA0 + k0);
    uint4 a1 = *(const uint4*)(gA1 + k0);
    uint4 b0 = *(const uint4*)(gB0 + k0);
    uint4 b1 = *(const uint4*)(gB1 + k0);
    *(uint4*)&As[(r0 << 5) + (ch << 3)] = a0;
    *(uint4*)&As[(r1 << 5) + (ch << 3)] = a1;
    *(uint4*)&Bs[(r0 << 5) + (ch << 3)] = b0;
    *(uint4*)&Bs[(r1 << 5) + (ch << 3)] = b1;
    __syncthreads();
    s16x8 af[4], bv[4];
    #pragma unroll
    for (int im = 0; im < 4; im++)
      af[im] = *(const s16x8*)&As[((wm + (im << 4) + l16) << 5) + (quad << 3)];
    #pragma unroll
    for (int in = 0; in < 4; in++)
      bv[in] = *(const s16x8*)&Bs[((wn + (in << 4) + l16) << 5) + (quad << 3)];
    __syncthreads();
    #pragma unroll
    for (int im = 0; im < 4; im++){
      #pragma unroll
      for (int in = 0; in < 4; in++)
        acc[im][in] = __builtin_amdgcn_mfma_f32_16x16x32_bf16(af[im], bv[in], acc[im][in], 0, 0, 0);
    }
  }

  #pragma unroll
  for (int im = 0; im < 4; im++){
    #pragma unroll
    for (int r = 0; r < 4; r++){
      int mrow = wm + (im << 4) + (quad << 2) + r;
      if (flg_s[mrow]){
        float g  = gate_s[mrow];
        int tok  = tok_s[mrow];
        size_t obase = ((((size_t)b << 12) + tok) << 10) + f0 + wn + l16;
        if (is_f32){
          float* o32 = (float*)outv;
          #pragma unroll
          for (int in = 0; in < 4; in++) o32[obase + (in << 4)] = acc[im][in][r] * g;
        } else {
          u16* o16 = (u16*)outv;
          #pragma unroll
          for (int in = 0; in < 4; in++) o16[obase + (in << 4)] = f2bf(acc[im][in][r] * g);
        }
      }
    }
  }
}

// ---------------- fallback GEMM (round-4 validated): on-the-fly convert + LDS transpose ----------------
__global__ __launch_bounds__(256) void k_gemm_slow(const void* __restrict__ xv, const void* __restrict__ Wv,
                                                   const float* __restrict__ gates,
                                                   const int* __restrict__ routed,
                                                   const int* __restrict__ winner,
                                                   const int* __restrict__ flag,
                                                   void* __restrict__ outv){
  __shared__ u16 As[128 * 32];
  __shared__ u16 Bw[32 * 132];
  __shared__ u16 Bs[128 * 32];
  __shared__ int   tok_s[128];
  __shared__ float gate_s[128];
  __shared__ int   flg_s[128];
  int is_f32 = *flag;
  int bx = blockIdx.x;
  int gemm = bx >> 5, tile = bx & 31;
  int b = gemm >> 3, e = gemm & 7;
  int mt = tile & 3, nt = tile >> 2;
  int tid = threadIdx.x;
  int w = tid >> 6, lane = tid & 63;
  int quad = lane >> 4, l16 = lane & 15;

  const int* idx_base = routed + (((b << 3) + e) << 9) + (mt << 7);

  if (tid < 128){
    int tok = idx_base[tid];
    int mg  = (mt << 7) + tid;
    int win = winner[(b << 12) + tok];
    tok_s[tid]  = tok;
    flg_s[tid]  = (win == ((mg << 3) | e)) ? 1 : 0;
    gate_s[tid] = gates[((((size_t)b << 12) + tok) << 3) + e];
  }
  __syncthreads();

  int r0 = tid >> 2;
  int ch = tid & 3;
  int r1 = r0 + 64;
  size_t offA0 = ((((size_t)b << 12) + tok_s[r0]) << 10) + (ch << 3);
  size_t offA1 = ((((size_t)b << 12) + tok_s[r1]) << 10) + (ch << 3);
  int f0 = nt << 7;
  int kkB0 = tid >> 4;
  int fcB  = tid & 15;
  size_t offB0 = ((size_t)e << 20) + ((size_t)kkB0 << 10) + f0 + (fcB << 3);
  size_t offB1 = offB0 + ((size_t)16 << 10);
  int f_loc = tid >> 1;
  int half  = tid & 1;

  f32x4 acc[4][4] = {};
  int wm = (w & 1) << 6, wn = (w >> 1) << 6;

  for (int k0 = 0; k0 < 1024; k0 += 32){
    uint4 a0, a1, b0, b1;
    if (is_f32){
      const float* xf = (const float*)xv;
      const float* wf = (const float*)Wv;
      a0 = pack8(*(const float4*)(xf + offA0 + k0), *(const float4*)(xf + offA0 + k0 + 4));
      a1 = pack8(*(const float4*)(xf + offA1 + k0), *(const float4*)(xf + offA1 + k0 + 4));
      b0 = pack8(*(const float4*)(wf + offB0 + ((size_t)k0 << 10)),
                 *(const float4*)(wf + offB0 + ((size_t)k0 << 10) + 4));
      b1 = pack8(*(const float4*)(wf + offB1 + ((size_t)k0 << 10)),
                 *(const float4*)(wf + offB1 + ((size_t)k0 << 10) + 4));
    } else {
      const u16* xh = (const u16*)xv;
      const u16* wh = (const u16*)Wv;
      a0 = *(const uint4*)(xh + offA0 + k0);
      a1 = *(const uint4*)(xh + offA1 + k0);
      b0 = *(const uint4*)(wh + offB0 + ((size_t)k0 << 10));
      b1 = *(const uint4*)(wh + offB1 + ((size_t)k0 << 10));
    }
    *(uint4*)&As[(r0 << 5) + (ch << 3)] = a0;
    *(uint4*)&As[(r1 << 5) + (ch << 3)] = a1;
    *(uint4*)&Bw[kkB0 * 132 + (fcB << 3)] = b0;
    *(uint4*)&Bw[(kkB0 + 16) * 132 + (fcB << 3)] = b1;
    __syncthreads();
    union { uint4 v[2]; u16 s[16]; } tv;
    #pragma unroll
    for (int j = 0; j < 16; j++) tv.s[j] = Bw[((half << 4) + j) * 132 + f_loc];
    *(uint4*)&Bs[(f_loc << 5) + (half << 4)]     = tv.v[0];
    *(uint4*)&Bs[(f_loc << 5) + (half << 4) + 8] = tv.v[1];
    __syncthreads();
    s16x8 af[4], bv[4];
    #pragma unroll
    for (int im = 0; im < 4; im++)
      af[im] = *(const s16x8*)&As[((wm + (im << 4) + l16) << 5) + (quad << 3)];
    #pragma unroll
    for (int in = 0; in < 4; in++)
      bv[in] = *(const s16x8*)&Bs[((wn + (in << 4) + l16) << 5) + (quad << 3)];
    __syncthreads();
    #pragma unroll
    for (int im = 0; im < 4; im++){
      #pragma unroll
      for (int in = 0; in < 4; in++)
        acc[im][in] = __builtin_amdgcn_mfma_f32_16x16x32_bf16(af[im], bv[in], acc[im][in], 0, 0, 0);
    }
  }

  #pragma unroll
  for (int im = 0; im < 4; im++){
    #pragma unroll
    for (int r = 0; r < 4; r++){
      int mrow = wm + (im << 4) + (quad << 2) + r;
      if (flg_s[mrow]){
        float g  = gate_s[mrow];
        int tok  = tok_s[mrow];
        size_t obase = ((((size_t)b << 12) + tok) << 10) + f0 + wn + l16;
        if (is_f32){
          float* o32 = (float*)outv;
          #pragma unroll
          for (int in = 0; in < 4; in++) o32[obase + (in << 4)] = acc[im][in][r] * g;
        } else {
          u16* o16 = (u16*)outv;
          #pragma unroll
          for (int in = 0; in < 4; in++) o16[obase + (in << 4)] = f2bf(acc[im][in][r] * g);
        }
      }
    }
  }
}

extern "C" void kernel_launch(void* const* d_in, const int* in_sizes, int n_in,
                              void* d_out, int out_size, void* d_ws, size_t ws_size,
                              hipStream_t stream){
  const void* x  = d_in[0];   // (4,4096,1024)
  const void* gw = d_in[1];   // (1024,8)
  const void* W  = d_in[2];   // (8,1024,1024)
  char* ws = (char*)d_ws;
  float* gates  = (float*)ws;                               // 524288 B
  int*   winner = (int*)(ws + 524288);                      // 65536 B
  int*   routed = (int*)(ws + 589824);                      // 65536 B
  int*   flag   = (int*)(ws + 655360);                      // 256 B (padded)
  u16*   xb     = (u16*)(ws + 655616);                      // 33554432 B
  u16*   WT     = (u16*)(ws + 655616 + 33554432);           // 16777216 B
  size_t need_fast = 655616ull + 33554432ull + 16777216ull; // ~48.6 MiB
  bool fast = ws_size >= need_fast;

  hipMemsetAsync(winner, 0xFF, 65536, stream);
  hipLaunchKernelGGL(k_detect,   dim3(1),    dim3(64),   0, stream, (const u32*)x, flag);
  hipLaunchKernelGGL(k_zero,     dim3(4096), dim3(256),  0, stream, (uint4*)d_out, flag, out_size);
  hipLaunchKernelGGL(k_logits,   dim3(4096), dim3(256),  0, stream, x, gw, flag, gates);
  hipLaunchKernelGGL(k_sinkhorn, dim3(4),    dim3(1024), 0, stream, gates);
  hipLaunchKernelGGL(k_rank,     dim3(1024), dim3(256),  0, stream, gates, routed, winner);
  if (fast){
    hipLaunchKernelGGL(k_cvt_x,  dim3(8192), dim3(256),  0, stream, x, flag, xb);
    hipLaunchKernelGGL(k_cvt_wt, dim3(2048), dim3(256),  0, stream, W, flag, WT);
    hipLaunchKernelGGL(k_gemm_fast, dim3(1024), dim3(256), 0, stream, xb, WT, gates, routed, winner,
                       flag, d_out);
  } else {
    hipLaunchKernelGGL(k_gemm_slow, dim3(1024), dim3(256), 0, stream, x, W, gates, routed, winner,
                       flag, d_out);
  }
}